// Round 10
// baseline (1191.550 us; speedup 1.0000x reference)
//
#include <hip/hip_runtime.h>

typedef _Float16 half2v __attribute__((ext_vector_type(2)));
typedef _Float16 f16x8  __attribute__((ext_vector_type(8)));
typedef float    f32x4  __attribute__((ext_vector_type(4)));

#define T_LEN 1024
#define NBATCH 1024
#define HID 20
#define G_B 2       // batches per block (lane-parallel: chains/stream = 2)
#define PPITCH 84   // pre-gate LDS row pitch in dwords

#if defined(__has_builtin)
#if __has_builtin(__builtin_amdgcn_fdot2)
#define HAVE_FDOT2 1
#endif
#endif

#define NLOG2E  -1.4426950408889634f   // -log2(e):  sigmoid gates
#define N2LOG2E -2.8853900817779268f   // -2log2(e): tanh gates

__device__ __forceinline__ float fdot2_(half2v a, half2v b, float c) {
#ifdef HAVE_FDOT2
    return __builtin_amdgcn_fdot2(a, b, c, false);
#else
    return c + (float)a[0] * (float)b[0] + (float)a[1] * (float)b[1];
#endif
}

__device__ __forceinline__ half2v pack2(float a, float b) {
    half2v r; r[0] = (_Float16)a; r[1] = (_Float16)b; return r;
}

// Load 20 f16 (32-half row, 16B-aligned) into 10 half2 (LDS broadcast).
__device__ __forceinline__ void load_h20(const _Float16* row, half2v hp[10]) {
    uint4 q0 = *(const uint4*)(row);
    uint4 q1 = *(const uint4*)(row + 8);
    uint2 q2 = *(const uint2*)(row + 16);
    hp[0] = __builtin_bit_cast(half2v, q0.x);
    hp[1] = __builtin_bit_cast(half2v, q0.y);
    hp[2] = __builtin_bit_cast(half2v, q0.z);
    hp[3] = __builtin_bit_cast(half2v, q0.w);
    hp[4] = __builtin_bit_cast(half2v, q1.x);
    hp[5] = __builtin_bit_cast(half2v, q1.y);
    hp[6] = __builtin_bit_cast(half2v, q1.z);
    hp[7] = __builtin_bit_cast(half2v, q1.w);
    hp[8] = __builtin_bit_cast(half2v, q2.x);
    hp[9] = __builtin_bit_cast(half2v, q2.y);
}

// 20-element dot, two depth-5 chains, seeded. EXACT R18 op order (frozen).
__device__ __forceinline__ float dot20s(const half2v W[10], const half2v h[10],
                                        float seed) {
    float a0 = seed, a1 = 0.f;
#pragma unroll
    for (int k = 0; k < 5; ++k) {
        a0 = fdot2_(W[k],     h[k],     a0);
        a1 = fdot2_(W[k + 5], h[k + 5], a1);
    }
    return a0 + a1;
}

// R25: fuse the 3 layer-waves into ONE wave with an in-wave pipeline.
// Iteration n computes L0@t=n, L1@t=n-1, L2@t=n-2 -- three INDEPENDENT
// chains (all inputs were written in iteration n-1; ping-pong LDS slots
// rd/wr) -> ILP-3 hides each chain's dot/trans/LDS latency, no barriers
// at all (single wave, in-order DS). Per-chain math is verbatim R18:
// dot20s order, cell order, p-add order, per-step ih-MFMA computes the
// exact values R18's interval ih-MFMA computed. Self-check: absmax must
// be exactly 1.953125e-3 (bit-identical to R18).
// R24 lesson applied: chains/stream stays 2 (lane-parallel batches);
// grid 512 x 64thr = 2 waves/CU; wall = per-wave issue, not occupancy.
__global__ void __launch_bounds__(64, 1) lstm3_r25(
    const float* __restrict__ x,
    const float* __restrict__ wih0, const float* __restrict__ whh0,
    const float* __restrict__ bih0, const float* __restrict__ bhh0,
    const float* __restrict__ wih1, const float* __restrict__ whh1,
    const float* __restrict__ bih1, const float* __restrict__ bhh1,
    const float* __restrict__ wih2, const float* __restrict__ whh2,
    const float* __restrict__ bih2, const float* __restrict__ bhh2,
    const float* __restrict__ fcw, const float* __restrict__ fcb,
    float* __restrict__ out)
{
    __shared__ __align__(16) float xs[G_B * T_LEN];          // [t][g] 8KB
    __shared__ __align__(16) _Float16 hbuf[3][2][G_B * 32];  // layer, parity
    __shared__ __align__(16) float pbuf[2][G_B][PPITCH];     // L1,L2 ih pre

    const int lane = threadIdx.x;         // 64 threads = 1 wave
    const long b_base = (long)blockIdx.x * G_B;

    {
        const float* xg = x + b_base * T_LEN;
        for (int i = lane; i < G_B * T_LEN; i += 64) {
            const int t = i & (T_LEN - 1);
            const int g = i >> 10;
            xs[2 * t + g] = xg[i];
        }
        for (int i = lane; i < 3 * 2 * G_B * 32; i += 64)
            ((_Float16*)hbuf)[i] = (_Float16)0.0f;
        // single wave: in-order DS, no barrier needed anywhere
    }

    const bool act = lane < G_B * HID;
    const int g = act ? (lane / HID) : 0;
    const int j = act ? (lane % HID) : 0;

    const float* whhs[3] = {whh0, whh1, whh2};
    const float* wihs[3] = {wih0, wih1, wih2};
    const float* bihs[3] = {bih0, bih1, bih2};
    const float* bhhs[3] = {bhh0, bhh1, bhh2};

    // Per-layer gate rows of unit j (pre-scaled), biases, L0 scalar wx.
    half2v Whh[3][4][10];
    float  bias[3][4];
    float  wx[4];
#pragma unroll
    for (int l = 0; l < 3; ++l) {
#pragma unroll
        for (int gt = 0; gt < 4; ++gt) {
            const float sc = (gt == 2) ? N2LOG2E : NLOG2E;
            const int r = gt * HID + j;
#pragma unroll
            for (int k4 = 0; k4 < 5; ++k4) {
                float4 v = *(const float4*)(whhs[l] + r * HID + 4 * k4);
                Whh[l][gt][2 * k4]     = pack2(sc * v.x, sc * v.y);
                Whh[l][gt][2 * k4 + 1] = pack2(sc * v.z, sc * v.w);
            }
            bias[l][gt] = sc * (bihs[l][r] + bhhs[l][r]);
        }
    }
#pragma unroll
    for (int gt = 0; gt < 4; ++gt)
        wx[gt] = ((gt == 2) ? N2LOG2E : NLOG2E) * wih0[gt * HID + j];

    // B fragments for the per-step ih MFMAs (L1,L2) + transposed scatter col.
    f16x8 WihB[2][5];
    int col4[5];
    {
        const int kc = (lane >> 4) * 8;
        const int coln = lane & 15;
#pragma unroll
        for (int t = 0; t < 5; ++t) {
            const int n = t * 16 + coln;          // gate-row 0..79
            const int gtn = n / HID;
            const float sc = (gtn == 2) ? N2LOG2E : NLOG2E;
            col4[t] = (n % HID) * 4 + gtn;
#pragma unroll
            for (int l = 0; l < 2; ++l) {
                f16x8 v;
#pragma unroll
                for (int e = 0; e < 8; ++e) {
                    const int k = kc + e;
                    v[e] = (_Float16)((k < HID) ? sc * wihs[l + 1][n * HID + k]
                                                : 0.f);
                }
                WihB[l][t] = v;
            }
        }
    }

    // A-frag offset (rows 0,1 = batches; rows>=2 harmless dupes) and own-h base
    const int aoff = (lane & 1) * 32 + (lane >> 4) * 8;
    const int hoo  = g * 32;

    float c0 = 0.f, c1 = 0.f, c2 = 0.f;
    const f32x4 z = {0.f, 0.f, 0.f, 0.f};

    auto cell = [&](const float p[4], float& c) -> float {
        // EXACT R18 activation sequence (two-rcp, shared-rcp pairs)
        const float ei = __builtin_exp2f(p[0]);
        const float ef = __builtin_exp2f(p[1]);
        const float eg = __builtin_exp2f(p[2]);
        const float eo = __builtin_exp2f(p[3]);
        const float sf = __builtin_amdgcn_rcpf(1.0f + ef);
        const float u  = (1.0f - eg) *
            __builtin_amdgcn_rcpf((1.0f + ei) * (1.0f + eg));
        c = sf * c + u;
        const float ec = __builtin_exp2f(N2LOG2E * c);
        return (1.0f - ec) *
            __builtin_amdgcn_rcpf((1.0f + eo) * (1.0f + ec));
    };

    auto body = [&](int n) {
        const int wr = n & 1;
        const int rd = wr ^ 1;
        // ---------- L0: t = n ----------
        {
            half2v ho[10];
            load_h20(&hbuf[0][rd][hoo], ho);          // h0(t-1)
            const int tx = (n < T_LEN) ? n : (T_LEN - 1);
            const float xt = xs[2 * tx + g];
            float p[4];
#pragma unroll
            for (int gt = 0; gt < 4; ++gt)
                p[gt] = dot20s(Whh[0][gt], ho, bias[0][gt]) + wx[gt] * xt;
            const float hn = cell(p, c0);
            if (act) hbuf[0][wr][hoo + j] = (_Float16)hn;
        }
        // ---------- L1: t = n-1 ----------
        {
            const f16x8 af = *(const f16x8*)(&hbuf[0][rd][0] + aoff);  // h0(t)
            f32x4 acc[5];
#pragma unroll
            for (int t = 0; t < 5; ++t)
                acc[t] = __builtin_amdgcn_mfma_f32_16x16x32_f16(
                    af, WihB[0][t], z, 0, 0, 0);
            if (lane < 16) {
#pragma unroll
                for (int t = 0; t < 5; ++t) {
                    pbuf[0][0][col4[t]] = acc[t][0];   // C row 0 = batch 0
                    pbuf[0][1][col4[t]] = acc[t][1];   // C row 1 = batch 1
                }
            }
            half2v ho[10];
            load_h20(&hbuf[1][rd][hoo], ho);          // h1(t-1)
            const f32x4 pf = *(const f32x4*)&pbuf[0][g][4 * j];
            float p[4];
#pragma unroll
            for (int gt = 0; gt < 4; ++gt)
                p[gt] = dot20s(Whh[1][gt], ho, bias[1][gt]) + pf[gt];
            const float hn = cell(p, c1);
            if (act) hbuf[1][wr][hoo + j] = (_Float16)hn;
        }
        // ---------- L2: t = n-2 ----------
        {
            const f16x8 af = *(const f16x8*)(&hbuf[1][rd][0] + aoff);  // h1(t)
            f32x4 acc[5];
#pragma unroll
            for (int t = 0; t < 5; ++t)
                acc[t] = __builtin_amdgcn_mfma_f32_16x16x32_f16(
                    af, WihB[1][t], z, 0, 0, 0);
            if (lane < 16) {
#pragma unroll
                for (int t = 0; t < 5; ++t) {
                    pbuf[1][0][col4[t]] = acc[t][0];
                    pbuf[1][1][col4[t]] = acc[t][1];
                }
            }
            half2v ho[10];
            load_h20(&hbuf[2][rd][hoo], ho);          // h2(t-1)
            const f32x4 pf = *(const f32x4*)&pbuf[1][g][4 * j];
            float p[4];
#pragma unroll
            for (int gt = 0; gt < 4; ++gt)
                p[gt] = dot20s(Whh[2][gt], ho, bias[2][gt]) + pf[gt];
            const float hn = cell(p, c2);
            if (act) hbuf[2][wr][hoo + j] = (_Float16)hn;
        }
    };

    // Warmup peel: L1 garbage at n=0, L2 garbage at n=0,1. oA is recomputed
    // from LDS every iteration, so only c-state + garbage-h need fixing.
    body(0);
    c1 = 0.f; c2 = 0.f;
    if (act) hbuf[1][0][hoo + j] = (_Float16)0.0f;   // erase garbage h1(-1)
    body(1);
    c2 = 0.f;
    if (act) hbuf[2][1][hoo + j] = (_Float16)0.0f;   // erase garbage h2(-1)

#pragma unroll 1
    for (int n = 2; n < T_LEN + 2; ++n)
        body(n);
    // Tail (n=1024,1025): L0/L1 compute dead values (x clamped); every live
    // input (h0(1023)@slot1, h1(1023)@slot0) is real. h2(1023) written at
    // n=1025 to slot 1.

    // FC epilogue (R18's exact order)
    if (lane < 2 * G_B) {
        const int gg = lane >> 1, o = lane & 1;
        float acc = fcb[o];
        const _Float16* h2 = &hbuf[2][(T_LEN + 1) & 1][gg * 32];
#pragma unroll
        for (int k = 0; k < HID; ++k)
            acc += fcw[o * HID + k] * (float)h2[k];
        out[(b_base + gg) * 2 + o] = acc;
    }
}

extern "C" void kernel_launch(void* const* d_in, const int* in_sizes, int n_in,
                              void* d_out, int out_size, void* d_ws, size_t ws_size,
                              hipStream_t stream) {
    const float* x    = (const float*)d_in[0];
    const float* wih0 = (const float*)d_in[1];
    const float* whh0 = (const float*)d_in[2];
    const float* bih0 = (const float*)d_in[3];
    const float* bhh0 = (const float*)d_in[4];
    const float* wih1 = (const float*)d_in[5];
    const float* whh1 = (const float*)d_in[6];
    const float* bih1 = (const float*)d_in[7];
    const float* bhh1 = (const float*)d_in[8];
    const float* wih2 = (const float*)d_in[9];
    const float* whh2 = (const float*)d_in[10];
    const float* bih2 = (const float*)d_in[11];
    const float* bhh2 = (const float*)d_in[12];
    const float* fcw  = (const float*)d_in[13];
    const float* fcb  = (const float*)d_in[14];

    lstm3_r25<<<dim3(NBATCH / G_B), dim3(64), 0, stream>>>(
        x, wih0, whh0, bih0, bhh0,
        wih1, whh1, bih1, bhh1,
        wih2, whh2, bih2, bhh2,
        fcw, fcb, (float*)d_out);
}

// Round 11
// 1032.448 us; speedup vs baseline: 1.1541x; 1.1541x over previous
//
#include <hip/hip_runtime.h>

typedef _Float16 half2v __attribute__((ext_vector_type(2)));
typedef _Float16 f16x8  __attribute__((ext_vector_type(8)));
typedef float    f32x4  __attribute__((ext_vector_type(4)));

#define T_LEN 1024
#define NBATCH 1024
#define HID 20
#define G_B 2       // batches per block (lane-parallel chains)
#define PPITCH 84   // pre-gate LDS row pitch in dwords

#if defined(__has_builtin)
#if __has_builtin(__builtin_amdgcn_fdot2)
#define HAVE_FDOT2 1
#endif
#endif

#define NLOG2E  -1.4426950408889634f   // -log2(e):  sigmoid gates
#define N2LOG2E -2.8853900817779268f   // -2log2(e): tanh gates

template <int V> struct ic { static constexpr int value = V; };

__device__ __forceinline__ float fdot2_(half2v a, half2v b, float c) {
#ifdef HAVE_FDOT2
    return __builtin_amdgcn_fdot2(a, b, c, false);
#else
    return c + (float)a[0] * (float)b[0] + (float)a[1] * (float)b[1];
#endif
}

__device__ __forceinline__ half2v pack2(float a, float b) {
    half2v r; r[0] = (_Float16)a; r[1] = (_Float16)b; return r;
}

// Load 20 f16 (32-half row, 16B-aligned) into 10 half2 (LDS broadcast).
__device__ __forceinline__ void load_h20(const _Float16* row, half2v hp[10]) {
    uint4 q0 = *(const uint4*)(row);
    uint4 q1 = *(const uint4*)(row + 8);
    uint2 q2 = *(const uint2*)(row + 16);
    hp[0] = __builtin_bit_cast(half2v, q0.x);
    hp[1] = __builtin_bit_cast(half2v, q0.y);
    hp[2] = __builtin_bit_cast(half2v, q0.z);
    hp[3] = __builtin_bit_cast(half2v, q0.w);
    hp[4] = __builtin_bit_cast(half2v, q1.x);
    hp[5] = __builtin_bit_cast(half2v, q1.y);
    hp[6] = __builtin_bit_cast(half2v, q1.z);
    hp[7] = __builtin_bit_cast(half2v, q1.w);
    hp[8] = __builtin_bit_cast(half2v, q2.x);
    hp[9] = __builtin_bit_cast(half2v, q2.y);
}

// 20-element dot, two depth-5 chains, seeded. EXACT R18 op order (frozen).
__device__ __forceinline__ float dot20s(const half2v W[10], const half2v h[10],
                                        float seed) {
    float a0 = seed, a1 = 0.f;
#pragma unroll
    for (int k = 0; k < 5; ++k) {
        a0 = fdot2_(W[k],     h[k],     a0);
        a1 = fdot2_(W[k + 5], h[k + 5], a1);
    }
    return a0 + a1;
}

// R26 = R25 (bit-identical fused 3-layer pipeline, 1 wave, 0 barriers) with
// the FALSE LDS DEPENDENCIES removed (R25 post-mortem: runtime wr/rd parity
// made hbuf[l][wr] stores vs hbuf[l][rd] loads un-provably disjoint ->
// compiler serialized the 3 layer chains, 2719cy/iter = 3 x 900cy):
//  1. parity is a TEMPLATE CONSTANT (body<WR>, 2x-unrolled loop) so RD/WR
//     buffers are distinct constant offsets -> loads hoistable past stores.
//  2. loads manually hoisted: all RD reads (2 A-frags, 3 h-rows, x) at top;
//     MFMAs+scatter next; the 3 independent dots fill the scatter->pf gap;
//     3 independent cell chains at the end.
// Per-chain math is verbatim R25/R18 -> absmax must be exactly 1.953125e-3.
__global__ void __launch_bounds__(64, 1) lstm3_r26(
    const float* __restrict__ x,
    const float* __restrict__ wih0, const float* __restrict__ whh0,
    const float* __restrict__ bih0, const float* __restrict__ bhh0,
    const float* __restrict__ wih1, const float* __restrict__ whh1,
    const float* __restrict__ bih1, const float* __restrict__ bhh1,
    const float* __restrict__ wih2, const float* __restrict__ whh2,
    const float* __restrict__ bih2, const float* __restrict__ bhh2,
    const float* __restrict__ fcw, const float* __restrict__ fcb,
    float* __restrict__ out)
{
    __shared__ __align__(16) float xs[G_B * T_LEN];          // [t][g] 8KB
    __shared__ __align__(16) _Float16 hbuf[3][2][G_B * 32];  // layer, parity
    __shared__ __align__(16) float pbuf[2][G_B][PPITCH];     // L1,L2 ih pre

    const int lane = threadIdx.x;         // 64 threads = 1 wave
    const long b_base = (long)blockIdx.x * G_B;

    {
        const float* xg = x + b_base * T_LEN;
        for (int i = lane; i < G_B * T_LEN; i += 64) {
            const int t = i & (T_LEN - 1);
            const int g = i >> 10;
            xs[2 * t + g] = xg[i];
        }
        for (int i = lane; i < 3 * 2 * G_B * 32; i += 64)
            ((_Float16*)hbuf)[i] = (_Float16)0.0f;
        // single wave: in-order DS, no barrier needed anywhere
    }

    const bool act = lane < G_B * HID;
    const int g = act ? (lane / HID) : 0;
    const int j = act ? (lane % HID) : 0;

    const float* whhs[3] = {whh0, whh1, whh2};
    const float* wihs[3] = {wih0, wih1, wih2};
    const float* bihs[3] = {bih0, bih1, bih2};
    const float* bhhs[3] = {bhh0, bhh1, bhh2};

    // Per-layer gate rows of unit j (pre-scaled), biases, L0 scalar wx.
    half2v Whh[3][4][10];
    float  bias[3][4];
    float  wx[4];
#pragma unroll
    for (int l = 0; l < 3; ++l) {
#pragma unroll
        for (int gt = 0; gt < 4; ++gt) {
            const float sc = (gt == 2) ? N2LOG2E : NLOG2E;
            const int r = gt * HID + j;
#pragma unroll
            for (int k4 = 0; k4 < 5; ++k4) {
                float4 v = *(const float4*)(whhs[l] + r * HID + 4 * k4);
                Whh[l][gt][2 * k4]     = pack2(sc * v.x, sc * v.y);
                Whh[l][gt][2 * k4 + 1] = pack2(sc * v.z, sc * v.w);
            }
            bias[l][gt] = sc * (bihs[l][r] + bhhs[l][r]);
        }
    }
#pragma unroll
    for (int gt = 0; gt < 4; ++gt)
        wx[gt] = ((gt == 2) ? N2LOG2E : NLOG2E) * wih0[gt * HID + j];

    // B fragments for the per-step ih MFMAs (L1,L2) + transposed scatter col.
    f16x8 WihB[2][5];
    int col4[5];
    {
        const int kc = (lane >> 4) * 8;
        const int coln = lane & 15;
#pragma unroll
        for (int t = 0; t < 5; ++t) {
            const int n = t * 16 + coln;          // gate-row 0..79
            const int gtn = n / HID;
            const float sc = (gtn == 2) ? N2LOG2E : NLOG2E;
            col4[t] = (n % HID) * 4 + gtn;
#pragma unroll
            for (int l = 0; l < 2; ++l) {
                f16x8 v;
#pragma unroll
                for (int e = 0; e < 8; ++e) {
                    const int k = kc + e;
                    v[e] = (_Float16)((k < HID) ? sc * wihs[l + 1][n * HID + k]
                                                : 0.f);
                }
                WihB[l][t] = v;
            }
        }
    }

    // A-frag offset (rows = batch parity dupes) and own-h lane base
    const int aoff = (lane & 1) * 32 + (lane >> 4) * 8;
    const int hoo  = g * 32;

    float c0 = 0.f, c1 = 0.f, c2 = 0.f;
    const f32x4 z = {0.f, 0.f, 0.f, 0.f};

    auto cell = [&](const float p[4], float& c) -> float {
        // EXACT R18 activation sequence (two-rcp, shared-rcp pairs)
        const float ei = __builtin_exp2f(p[0]);
        const float ef = __builtin_exp2f(p[1]);
        const float eg = __builtin_exp2f(p[2]);
        const float eo = __builtin_exp2f(p[3]);
        const float sf = __builtin_amdgcn_rcpf(1.0f + ef);
        const float u  = (1.0f - eg) *
            __builtin_amdgcn_rcpf((1.0f + ei) * (1.0f + eg));
        c = sf * c + u;
        const float ec = __builtin_exp2f(N2LOG2E * c);
        return (1.0f - ec) *
            __builtin_amdgcn_rcpf((1.0f + eo) * (1.0f + ec));
    };

    auto body = [&](auto wrc, int n) {
        constexpr int WR = decltype(wrc)::value;
        constexpr int RD = WR ^ 1;

        // ---- phase 1: ALL loads from RD buffers (no store aliases) ----
        const f16x8 af0 = *(const f16x8*)(&hbuf[0][RD][0] + aoff);  // h0(t-1)
        const f16x8 af1 = *(const f16x8*)(&hbuf[1][RD][0] + aoff);  // h1(t-1)
        half2v ho0[10], ho1[10], ho2[10];
        load_h20(&hbuf[0][RD][hoo], ho0);
        load_h20(&hbuf[1][RD][hoo], ho1);
        load_h20(&hbuf[2][RD][hoo], ho2);
        const int tx = (n < T_LEN) ? n : (T_LEN - 1);
        const float xt = xs[2 * tx + g];

        // ---- phase 2: pregate MFMAs + transposed scatter ----
        f32x4 acc0[5], acc1[5];
#pragma unroll
        for (int t = 0; t < 5; ++t)
            acc0[t] = __builtin_amdgcn_mfma_f32_16x16x32_f16(
                af0, WihB[0][t], z, 0, 0, 0);
#pragma unroll
        for (int t = 0; t < 5; ++t)
            acc1[t] = __builtin_amdgcn_mfma_f32_16x16x32_f16(
                af1, WihB[1][t], z, 0, 0, 0);
        if (lane < 16) {
#pragma unroll
            for (int t = 0; t < 5; ++t) {
                pbuf[0][0][col4[t]] = acc0[t][0];   // C row 0 = batch 0
                pbuf[0][1][col4[t]] = acc0[t][1];   // C row 1 = batch 1
                pbuf[1][0][col4[t]] = acc1[t][0];
                pbuf[1][1][col4[t]] = acc1[t][1];
            }
        }

        // ---- phase 3: three independent hh-dots (fill the scatter gap) ----
        float d0[4], d1[4], d2[4];
#pragma unroll
        for (int gt = 0; gt < 4; ++gt)
            d0[gt] = dot20s(Whh[0][gt], ho0, bias[0][gt]) + wx[gt] * xt;
#pragma unroll
        for (int gt = 0; gt < 4; ++gt)
            d1[gt] = dot20s(Whh[1][gt], ho1, bias[1][gt]);
#pragma unroll
        for (int gt = 0; gt < 4; ++gt)
            d2[gt] = dot20s(Whh[2][gt], ho2, bias[2][gt]);

        // ---- phase 4: pregate reads + p assembly ----
        const f32x4 pf0 = *(const f32x4*)&pbuf[0][g][4 * j];
        const f32x4 pf1 = *(const f32x4*)&pbuf[1][g][4 * j];
        float p1[4], p2[4];
#pragma unroll
        for (int gt = 0; gt < 4; ++gt) {
            p1[gt] = d1[gt] + pf0[gt];
            p2[gt] = d2[gt] + pf1[gt];
        }

        // ---- phase 5: three independent cells + WR writes ----
        const float hn0 = cell(d0, c0);
        if (act) hbuf[0][WR][hoo + j] = (_Float16)hn0;
        const float hn1 = cell(p1, c1);
        if (act) hbuf[1][WR][hoo + j] = (_Float16)hn1;
        const float hn2 = cell(p2, c2);
        if (act) hbuf[2][WR][hoo + j] = (_Float16)hn2;
    };

    // Warmup peel (R25's proven sequence): L1 garbage at n=0, L2 at n=0,1.
    body(ic<0>{}, 0);
    c1 = 0.f; c2 = 0.f;
    if (act) hbuf[1][0][hoo + j] = (_Float16)0.0f;   // erase garbage h1(-1)
    body(ic<1>{}, 1);
    c2 = 0.f;
    if (act) hbuf[2][1][hoo + j] = (_Float16)0.0f;   // erase garbage h2(-1)

#pragma unroll 1
    for (int n = 2; n < T_LEN + 2; n += 2) {
        body(ic<0>{}, n);
        body(ic<1>{}, n + 1);
    }
    // Tail (n=1024,1025): dead L0/L1 values (x clamped); h2(1023) lands in
    // slot parity 1.

    // FC epilogue (R18's exact order)
    if (lane < 2 * G_B) {
        const int gg = lane >> 1, o = lane & 1;
        float acc = fcb[o];
        const _Float16* h2 = &hbuf[2][(T_LEN + 1) & 1][gg * 32];
#pragma unroll
        for (int k = 0; k < HID; ++k)
            acc += fcw[o * HID + k] * (float)h2[k];
        out[(b_base + gg) * 2 + o] = acc;
    }
}

extern "C" void kernel_launch(void* const* d_in, const int* in_sizes, int n_in,
                              void* d_out, int out_size, void* d_ws, size_t ws_size,
                              hipStream_t stream) {
    const float* x    = (const float*)d_in[0];
    const float* wih0 = (const float*)d_in[1];
    const float* whh0 = (const float*)d_in[2];
    const float* bih0 = (const float*)d_in[3];
    const float* bhh0 = (const float*)d_in[4];
    const float* wih1 = (const float*)d_in[5];
    const float* whh1 = (const float*)d_in[6];
    const float* bih1 = (const float*)d_in[7];
    const float* bhh1 = (const float*)d_in[8];
    const float* wih2 = (const float*)d_in[9];
    const float* whh2 = (const float*)d_in[10];
    const float* bih2 = (const float*)d_in[11];
    const float* bhh2 = (const float*)d_in[12];
    const float* fcw  = (const float*)d_in[13];
    const float* fcb  = (const float*)d_in[14];

    lstm3_r26<<<dim3(NBATCH / G_B), dim3(64), 0, stream>>>(
        x, wih0, whh0, bih0, bhh0,
        wih1, whh1, bih1, bhh1,
        wih2, whh2, bih2, bhh2,
        fcw, fcb, (float*)d_out);
}